// Round 1
// 567.160 us; speedup vs baseline: 1.1020x; 1.1020x over previous
//
#include <hip/hip_runtime.h>
#include <hip/hip_bf16.h>
#include <cstdint>

#define TOKENS 8192
#define IN_F 4096
#define OUT_F 4096

typedef __bf16 bf16x8 __attribute__((ext_vector_type(8)));
typedef float f32x4 __attribute__((ext_vector_type(4)));

// ---------------------------------------------------------------------------
// Last-write-wins scatter, 32-bit: M[cell] = max nnz-index touching cell.
// M memset to 0xFF (= -1) beforehand; i >= 0 always wins. No w read here.
// ---------------------------------------------------------------------------
__global__ void scatter_max_kernel(const int* __restrict__ row,
                                   const int* __restrict__ col,
                                   int* __restrict__ M, int nnz) {
    int i = blockIdx.x * blockDim.x + threadIdx.x;
    if (i < nnz) {
        atomicMax(&M[(size_t)row[i] * IN_F + col[i]], i);
    }
}

// ---------------------------------------------------------------------------
// Fused streaming pass: blocks [0, eb) read M sequentially, gather the
// winning weight w[idx] (w is 6.5 MB -> L2-resident) and write bf16 W
// (every cell written -> no W memset). Blocks [eb, ...) convert x fp32->bf16.
// ---------------------------------------------------------------------------
__global__ void extract_convert_kernel(const int* __restrict__ M,
                                       const float* __restrict__ w,
                                       __bf16* __restrict__ Wb,
                                       const float* __restrict__ x,
                                       __bf16* __restrict__ xb,
                                       int eb) {
    if ((int)blockIdx.x < eb) {
        size_t base = ((size_t)blockIdx.x * 256 + threadIdx.x) * 8;
        int4 m0 = *(const int4*)(M + base);
        int4 m1 = *(const int4*)(M + base + 4);
        int idx[8] = {m0.x, m0.y, m0.z, m0.w, m1.x, m1.y, m1.z, m1.w};
        bf16x8 o;
#pragma unroll
        for (int j = 0; j < 8; ++j) {
            o[j] = (idx[j] >= 0) ? (__bf16)w[idx[j]] : (__bf16)0.0f;
        }
        *(bf16x8*)(Wb + base) = o;
    } else {
        size_t base = ((size_t)(blockIdx.x - eb) * 256 + threadIdx.x) * 8;
        float4 v0 = *(const float4*)(x + base);
        float4 v1 = *(const float4*)(x + base + 4);
        bf16x8 o;
        o[0] = (__bf16)v0.x; o[1] = (__bf16)v0.y;
        o[2] = (__bf16)v0.z; o[3] = (__bf16)v0.w;
        o[4] = (__bf16)v1.x; o[5] = (__bf16)v1.y;
        o[6] = (__bf16)v1.z; o[7] = (__bf16)v1.w;
        *(bf16x8*)(xb + base) = o;
    }
}

// ---------------------------------------------------------------------------
// GEMM: C[M,N] = A[M,K] * B[N,K]^T + bias  -- 256x256 8-phase schedule
// (HK-derived template: T2 XOR-swizzle + T3/T4 counted vmcnt + T5 setprio).
//
// 512 threads = 8 waves (2M x 4N), per-wave 128x64 output = acc[8][4] f32x4.
// BK=64, LDS = 2dbuf x (A 32K + B 32K) = 128 KiB (dynamic).
//
// Swizzle: physical 16B-chunk p of LDS row r holds logical chunk p^(r&7);
// staged via pre-swizzled GLOBAL source column (linear global_load_lds dest),
// read back with chunk = (kk*4 + (l>>4)) ^ (l&7). Every ds_read_b128 touches
// each bank exactly 8x (the b128 minimum) -> conflict-free.
//
// Schedule per iteration (2 K-tiles t,t+1; tiles alternate buf0/buf1):
//   P1: read A0,B01(t,buf0)   | stage B(t+1)->buf1 | MMA Q(mh0,n01)
//   P2: read B23(t)                                | MMA Q(mh0,n23)
//   P3: read A1(t)                                 | MMA Q(mh1,n23)
//   P4: re-read B01(t)        | stage A(t+2)->buf0 | MMA Q(mh1,n01) vmcnt(4)
//   P5..P8: same on tile t+1 (buf1), staging B(t+2)->buf0, A(t+3)->buf1.
// vmcnt(4) at P4 guarantees the P1 B-stage landed (tile t+1 complete);
// vmcnt(4) at P8 guarantees A(t+2)+B(t+2) landed. Never vmcnt(0) in loop.
// Every stage is issued only after the barrier following the last ds_read of
// the LDS region it overwrites (A(t) free after P3, B(t) free after P4, etc).
// ---------------------------------------------------------------------------
#define BK 64
#define NT (IN_F / BK)

__global__ __launch_bounds__(512, 2) void gemm256_kernel(
    const __bf16* __restrict__ A,   // [TOKENS, IN_F] bf16
    const __bf16* __restrict__ B,   // [OUT_F, IN_F] bf16
    const float* __restrict__ bias, // [OUT_F]
    float* __restrict__ C) {        // [TOKENS, OUT_F]
    extern __shared__ __bf16 sm[];  // A[2][256][64] @ el 0, B[2][256][64] @ el 32768

    const int tid = threadIdx.x;
    const int l   = tid & 63;
    const int wid = tid >> 6;        // 0..7
    const int wm  = wid >> 2;        // 0..1
    const int wn  = wid & 3;         // 0..3

    // XCD-aware swizzle: 512 wgs, 512%8==0 -> simple variant is bijective.
    const int bid = blockIdx.y * 16 + blockIdx.x;
    const int swz = (bid & 7) * 64 + (bid >> 3);
    const int n0 = (swz & 15) * 256;
    const int m0 = (swz >> 4) * 256;

    // Staging: thread covers row (tid>>3) of each 64-row group, source chunk
    // pre-swizzled so linear LDS slot (r, p) receives logical chunk p^(r&7).
    const int srow   = tid >> 3;                    // 0..63
    const int schunk = (tid & 7) ^ (srow & 7);      // swizzled 16B source chunk
    const __bf16* gA = A + (size_t)(m0 + srow) * IN_F + schunk * 8;
    const __bf16* gB = B + (size_t)(n0 + srow) * IN_F + schunk * 8;
    const int ldsw = wid * 512;                     // wave's element offset in each 64-row group

#define GLD(SRC, LEL)                                                          \
    __builtin_amdgcn_global_load_lds(                                          \
        (unsigned int __attribute__((address_space(1)))*)(SRC),                \
        (unsigned int __attribute__((address_space(3)))*)(sm + (LEL)), 16, 0, 0);

#define STAGE_A(BUF, KT) {                                                     \
    GLD(gA + (KT),              (BUF)*16384 + 0     + ldsw)                    \
    GLD(gA + 64*IN_F  + (KT),   (BUF)*16384 + 4096  + ldsw)                    \
    GLD(gA + 128*IN_F + (KT),   (BUF)*16384 + 8192  + ldsw)                    \
    GLD(gA + 192*IN_F + (KT),   (BUF)*16384 + 12288 + ldsw) }

#define STAGE_B(BUF, KT) {                                                     \
    GLD(gB + (KT),              32768 + (BUF)*16384 + 0     + ldsw)            \
    GLD(gB + 64*IN_F  + (KT),   32768 + (BUF)*16384 + 4096  + ldsw)            \
    GLD(gB + 128*IN_F + (KT),   32768 + (BUF)*16384 + 8192  + ldsw)            \
    GLD(gB + 192*IN_F + (KT),   32768 + (BUF)*16384 + 12288 + ldsw) }

    // Fragment addressing: row = (wave base + mh*64 + mf*16 + (l&15)),
    // logical chunk kk*4 + (l>>4), physical chunk = logical ^ (l&7)
    // (row&7 == l&7 since all row bases are multiples of 8).
    const int g    = l >> 4;                 // 0..3
    const int fr   = l & 15;
    const int ch0  = g ^ (l & 7);            // phys chunk for kk=0
    const int ch1  = ch0 ^ 4;                // phys chunk for kk=1
    const int arow = (wm * 128 + fr) * 64;   // element offset of lane's A row
    const int brow = (wn * 64 + fr) * 64;    // element offset of lane's B row

    f32x4 acc[8][4] = {};
    bf16x8 a[4][2], b[2][2];

#define LDA_H(BUF, MH) {                                                                  \
    _Pragma("unroll") for (int mf = 0; mf < 4; ++mf) {                                    \
        a[mf][0] = *(const bf16x8*)(sm + (BUF)*16384 + (MH)*4096 + arow + mf*1024 + ch0*8); \
        a[mf][1] = *(const bf16x8*)(sm + (BUF)*16384 + (MH)*4096 + arow + mf*1024 + ch1*8); } }

#define LDB_P(BUF, NB) {                                                                  \
    _Pragma("unroll") for (int j = 0; j < 2; ++j) {                                       \
        b[j][0] = *(const bf16x8*)(sm + 32768 + (BUF)*16384 + brow + ((NB)+j)*1024 + ch0*8); \
        b[j][1] = *(const bf16x8*)(sm + 32768 + (BUF)*16384 + brow + ((NB)+j)*1024 + ch1*8); } }

#define MMA(MH, NB) {                                                          \
    __builtin_amdgcn_s_setprio(1);                                             \
    _Pragma("unroll") for (int mf = 0; mf < 4; ++mf)                           \
    _Pragma("unroll") for (int j = 0; j < 2; ++j) {                            \
        acc[(MH)*4+mf][(NB)+j] = __builtin_amdgcn_mfma_f32_16x16x32_bf16(      \
            a[mf][0], b[j][0], acc[(MH)*4+mf][(NB)+j], 0, 0, 0);               \
        acc[(MH)*4+mf][(NB)+j] = __builtin_amdgcn_mfma_f32_16x16x32_bf16(      \
            a[mf][1], b[j][1], acc[(MH)*4+mf][(NB)+j], 0, 0, 0); }             \
    __builtin_amdgcn_s_setprio(0); }

#define BARRIER() { asm volatile("" ::: "memory");                             \
                    __builtin_amdgcn_s_barrier();                              \
                    asm volatile("" ::: "memory"); }
#define LGKM0()   asm volatile("s_waitcnt lgkmcnt(0)" ::: "memory");
#define VMC(N)    asm volatile("s_waitcnt vmcnt(" #N ")" ::: "memory");

    // Prologue: tile0 (A+B) -> buf0, tile1 A -> buf1; wait tile0 (8 oldest).
    STAGE_A(0, 0)
    STAGE_B(0, 0)
    STAGE_A(1, BK)
    VMC(4)
    BARRIER()

#pragma unroll 1
    for (int t = 0; t < NT; t += 2) {
        const int k1 = (t + 1) * BK;
        const int k2 = ((t + 2) & (NT - 1)) * BK;  // wraps harmlessly on last iter
        const int k3 = ((t + 3) & (NT - 1)) * BK;

        // ---- tile t from buf0 ----
        LDA_H(0, 0) LDB_P(0, 0) STAGE_B(1, k1)              // P1
        BARRIER() LGKM0() MMA(0, 0) BARRIER()
        LDB_P(0, 2)                                         // P2
        BARRIER() LGKM0() MMA(0, 2) BARRIER()
        LDA_H(0, 1)                                         // P3
        BARRIER() LGKM0() MMA(1, 2) BARRIER()
        LDB_P(0, 0) STAGE_A(0, k2)                          // P4
        BARRIER() LGKM0() MMA(1, 0) VMC(4) BARRIER()

        // ---- tile t+1 from buf1 ----
        LDA_H(1, 0) LDB_P(1, 0) STAGE_B(0, k2)              // P5
        BARRIER() LGKM0() MMA(0, 0) BARRIER()
        LDB_P(1, 2)                                         // P6
        BARRIER() LGKM0() MMA(0, 2) BARRIER()
        LDA_H(1, 1)                                         // P7
        BARRIER() LGKM0() MMA(1, 2) BARRIER()
        LDB_P(1, 0) STAGE_A(1, k3)                          // P8
        BARRIER() LGKM0() MMA(1, 0) VMC(4) BARRIER()
    }
    VMC(0)  // drain stray prefetches before LDS goes out of scope

    // Epilogue: C/D layout col = l&15, row = (l>>4)*4 + i.
    float bv[4];
#pragma unroll
    for (int nf = 0; nf < 4; ++nf) bv[nf] = bias[n0 + wn * 64 + nf * 16 + fr];
    const int r0 = m0 + wm * 128 + g * 4;
#pragma unroll
    for (int mh = 0; mh < 2; ++mh)
#pragma unroll
        for (int mf = 0; mf < 4; ++mf)
#pragma unroll
            for (int nf = 0; nf < 4; ++nf) {
                const int col = n0 + wn * 64 + nf * 16 + fr;
#pragma unroll
                for (int i = 0; i < 4; ++i)
                    C[(size_t)(r0 + mh * 64 + mf * 16 + i) * OUT_F + col] =
                        acc[mh * 4 + mf][nf][i] + bv[nf];
            }
}

extern "C" void kernel_launch(void* const* d_in, const int* in_sizes, int n_in,
                              void* d_out, int out_size, void* d_ws, size_t ws_size,
                              hipStream_t stream) {
    const float* x    = (const float*)d_in[0];
    const float* w    = (const float*)d_in[1];
    const float* bias = (const float*)d_in[2];
    const int*   row  = (const int*)d_in[3];
    const int*   col  = (const int*)d_in[4];
    float* out = (float*)d_out;
    const int nnz = in_sizes[3];

    // Workspace: xb (67 MB) + Wb (33.5 MB) in d_ws. Winner-index array M
    // (16.78M x 4B = 67 MB) borrows d_out (134 MB) -- GEMM overwrites it later.
    __bf16* xb = (__bf16*)d_ws;
    __bf16* Wb = (__bf16*)((char*)d_ws + (size_t)TOKENS * IN_F * 2);
    int* M = (int*)d_out;

    static bool attr_done = false;
    if (!attr_done) {
        hipFuncSetAttribute(reinterpret_cast<const void*>(gemm256_kernel),
                            hipFuncAttributeMaxDynamicSharedMemorySize, 131072);
        attr_done = true;
    }

    hipMemsetAsync(M, 0xFF, (size_t)OUT_F * IN_F * 4, stream);  // M = -1

    scatter_max_kernel<<<(nnz + 255) / 256, 256, 0, stream>>>(row, col, M, nnz);

    const int eb = OUT_F * IN_F / (256 * 8);        // 8192 extract blocks
    const int cb = TOKENS * IN_F / (256 * 8);       // 16384 convert blocks
    extract_convert_kernel<<<eb + cb, 256, 0, stream>>>(M, w, Wb, x, xb, eb);

    dim3 grid(OUT_F / 256, TOKENS / 256);           // (16, 32) = 512 wgs
    gemm256_kernel<<<grid, 512, 131072, stream>>>(xb, Wb, bias, out);
}

// Round 2
// 542.752 us; speedup vs baseline: 1.1516x; 1.0450x over previous
//
#include <hip/hip_runtime.h>
#include <hip/hip_bf16.h>
#include <cstdint>

#define TOKENS 8192
#define IN_F 4096
#define OUT_F 4096

typedef __bf16 bf16x8 __attribute__((ext_vector_type(8)));
typedef float f32x4 __attribute__((ext_vector_type(4)));

// ---------------------------------------------------------------------------
// Last-write-wins scatter: M[cell] = max nnz-index touching cell.
// ---------------------------------------------------------------------------
__global__ void scatter_max_kernel(const int* __restrict__ row,
                                   const int* __restrict__ col,
                                   int* __restrict__ M, int nnz) {
    int i = blockIdx.x * blockDim.x + threadIdx.x;
    if (i < nnz) {
        atomicMax(&M[(size_t)row[i] * IN_F + col[i]], i);
    }
}

// ---------------------------------------------------------------------------
// Fused streaming pass: extract winning weights -> bf16 W; convert x -> bf16.
// ---------------------------------------------------------------------------
__global__ void extract_convert_kernel(const int* __restrict__ M,
                                       const float* __restrict__ w,
                                       __bf16* __restrict__ Wb,
                                       const float* __restrict__ x,
                                       __bf16* __restrict__ xb,
                                       int eb) {
    if ((int)blockIdx.x < eb) {
        size_t base = ((size_t)blockIdx.x * 256 + threadIdx.x) * 8;
        int4 m0 = *(const int4*)(M + base);
        int4 m1 = *(const int4*)(M + base + 4);
        int idx[8] = {m0.x, m0.y, m0.z, m0.w, m1.x, m1.y, m1.z, m1.w};
        bf16x8 o;
#pragma unroll
        for (int j = 0; j < 8; ++j) {
            o[j] = (idx[j] >= 0) ? (__bf16)w[idx[j]] : (__bf16)0.0f;
        }
        *(bf16x8*)(Wb + base) = o;
    } else {
        size_t base = ((size_t)(blockIdx.x - eb) * 256 + threadIdx.x) * 8;
        float4 v0 = *(const float4*)(x + base);
        float4 v1 = *(const float4*)(x + base + 4);
        bf16x8 o;
        o[0] = (__bf16)v0.x; o[1] = (__bf16)v0.y;
        o[2] = (__bf16)v0.z; o[3] = (__bf16)v0.w;
        o[4] = (__bf16)v1.x; o[5] = (__bf16)v1.y;
        o[6] = (__bf16)v1.z; o[7] = (__bf16)v1.w;
        *(bf16x8*)(xb + base) = o;
    }
}

// ---------------------------------------------------------------------------
// GEMM: C = A * B^T + bias. 256x256 tile, BK=64, 8 waves (2Mx4N), 128KiB LDS.
//
// v2 schedule: 4 phases per K-tile, ONE barrier per phase, read-ahead-1.
// Each phase issues exactly 6 ds_read_b128 whose data is consumed by the
// NEXT phase's 16-MFMA cluster; before each barrier an explicit
// s_waitcnt lgkmcnt(6) drains the previous phase's reads (DS completes
// in-order), which both feeds the MMA and guarantees cross-wave region
// safety for stages issued >= 2 phases after the last read of a region.
//
// Per tile tau (buf X = tau&1, other buf Y; b01 regs ping-pong E/O):
//   F1: read b23(tau)@X(4) + a1(tau)mf0@X(2)      ; MMA(0,01)=aP x b01cur
//   F2: read a1(tau)mf1-3@X(6)                    ; MMA(0,23)=aP x b23
//       lgkmcnt(6)+vmcnt(0)  <- only A,B(tau+1) in flight: exactly what F3 needs
//   F3: stage B(tau+2)->X(4); read a0(tau+1)mf01@Y(4)+b01n n0@Y(2); MMA(1,23)
//   F4: stage A(tau+2)->X(4); read a0(tau+1)mf23@Y(4)+b01n n1@Y(2); MMA(1,01)
// Region safety (1 barrier/phase + lgkmcnt(6) at phase end):
//   stage B(tau+2)@F3 vs b23 reads issued F1: drained by F2-end lgkm(6). OK
//   stage A(tau+2)@F4 vs a1 reads issued F2: drained by F3-end lgkm(6). OK
//   reads of tile tau+1 @F3: vmcnt(0)@F2-end + barrier => staged data landed.
// ---------------------------------------------------------------------------
#define BK 64
#define NT (IN_F / BK)

__global__ __launch_bounds__(512, 1) void gemm256_kernel(
    const __bf16* __restrict__ A,   // [TOKENS, IN_F] bf16
    const __bf16* __restrict__ B,   // [OUT_F, IN_F] bf16
    const float* __restrict__ bias, // [OUT_F]
    float* __restrict__ C) {        // [TOKENS, OUT_F]
    extern __shared__ __bf16 sm[];  // A[2][256][64] @ 0, B[2][256][64] @ 32768

    const int tid = threadIdx.x;
    const int l   = tid & 63;
    const int wid = tid >> 6;        // 0..7
    const int wm  = wid >> 2;        // 0..1
    const int wn  = wid & 3;         // 0..3

    // XCD-aware swizzle: 512 wgs, divisible by 8 -> simple variant bijective.
    const int bid = blockIdx.y * 16 + blockIdx.x;
    const int swz = (bid & 7) * 64 + (bid >> 3);
    const int n0 = (swz & 15) * 256;
    const int m0 = (swz >> 4) * 256;

    // Staging: lane covers row tid>>3 of each 64-row group; source 16B-chunk
    // pre-swizzled so linear LDS slot (r,p) holds logical chunk p^(r&7).
    const int srow   = tid >> 3;
    const int schunk = (tid & 7) ^ (srow & 7);
    const __bf16* gA = A + (size_t)(m0 + srow) * IN_F + schunk * 8;
    const __bf16* gB = B + (size_t)(n0 + srow) * IN_F + schunk * 8;
    const int ldsw = wid * 512;

#define GLD(SRC, LEL)                                                          \
    __builtin_amdgcn_global_load_lds(                                          \
        (unsigned int __attribute__((address_space(1)))*)(SRC),                \
        (unsigned int __attribute__((address_space(3)))*)(sm + (LEL)), 16, 0, 0);

#define STAGE_A(BUF, KT) {                                                     \
    GLD(gA + (KT),              (BUF)*16384 + 0     + ldsw)                    \
    GLD(gA + 64*IN_F  + (KT),   (BUF)*16384 + 4096  + ldsw)                    \
    GLD(gA + 128*IN_F + (KT),   (BUF)*16384 + 8192  + ldsw)                    \
    GLD(gA + 192*IN_F + (KT),   (BUF)*16384 + 12288 + ldsw) }

#define STAGE_B(BUF, KT) {                                                     \
    GLD(gB + (KT),              32768 + (BUF)*16384 + 0     + ldsw)            \
    GLD(gB + 64*IN_F  + (KT),   32768 + (BUF)*16384 + 4096  + ldsw)            \
    GLD(gB + 128*IN_F + (KT),   32768 + (BUF)*16384 + 8192  + ldsw)            \
    GLD(gB + 192*IN_F + (KT),   32768 + (BUF)*16384 + 12288 + ldsw) }

    // Fragment addressing: row = base + fr, logical chunk kk*4 + (l>>4),
    // physical chunk = logical ^ (l&7) (row bases are multiples of 16).
    const int g    = l >> 4;
    const int fr   = l & 15;
    const int ch0  = g ^ (l & 7);
    const int ch1  = ch0 ^ 4;
    const int arow = (wm * 128 + fr) * 64;
    const int brow = (wn * 64 + fr) * 64;

    f32x4 acc[8][4] = {};
    bf16x8 aP[4][2], aQ[4][2], b01E[2][2], b01O[2][2], b23[2][2];

// one LDAF = 2 ds_read_b128 (kk=0,1); one LDBF = 2 ds_read_b128
#define LDAF(DST, MF, BUF, MH) {                                                             \
    DST[MF][0] = *(const bf16x8*)(sm + (BUF)*16384 + (MH)*4096 + arow + (MF)*1024 + ch0*8);  \
    DST[MF][1] = *(const bf16x8*)(sm + (BUF)*16384 + (MH)*4096 + arow + (MF)*1024 + ch1*8); }

#define LDBF(DST, J, BUF, NB) {                                                                    \
    DST[J][0] = *(const bf16x8*)(sm + 32768 + (BUF)*16384 + brow + ((NB)+(J))*1024 + ch0*8);       \
    DST[J][1] = *(const bf16x8*)(sm + 32768 + (BUF)*16384 + brow + ((NB)+(J))*1024 + ch1*8); }

#define MMAC(AR, BR, MB, NB) {                                                 \
    __builtin_amdgcn_s_setprio(1);                                             \
    _Pragma("unroll") for (int mf = 0; mf < 4; ++mf)                           \
    _Pragma("unroll") for (int j = 0; j < 2; ++j) {                            \
        acc[(MB)+mf][(NB)+j] = __builtin_amdgcn_mfma_f32_16x16x32_bf16(        \
            AR[mf][0], BR[j][0], acc[(MB)+mf][(NB)+j], 0, 0, 0);               \
        acc[(MB)+mf][(NB)+j] = __builtin_amdgcn_mfma_f32_16x16x32_bf16(        \
            AR[mf][1], BR[j][1], acc[(MB)+mf][(NB)+j], 0, 0, 0); }             \
    __builtin_amdgcn_s_setprio(0); }

// phase end: drain all but this phase's 6 reads, then barrier
#define PEND() { asm volatile("s_waitcnt lgkmcnt(6)" ::: "memory");            \
                 __builtin_amdgcn_s_barrier();                                 \
                 asm volatile("" ::: "memory"); }
#define PEND_VM() { asm volatile("s_waitcnt lgkmcnt(6) vmcnt(0)" ::: "memory");\
                    __builtin_amdgcn_s_barrier();                              \
                    asm volatile("" ::: "memory"); }

#define TILE(BUF, OBUF, BC, BN, KS) {                                          \
    /* F1 */                                                                   \
    LDBF(b23, 0, BUF, 2) LDBF(b23, 1, BUF, 2) LDAF(aQ, 0, BUF, 1)              \
    MMAC(aP, BC, 0, 0)                                                         \
    PEND()                                                                     \
    /* F2 */                                                                   \
    LDAF(aQ, 1, BUF, 1) LDAF(aQ, 2, BUF, 1) LDAF(aQ, 3, BUF, 1)                \
    MMAC(aP, b23, 0, 2)                                                        \
    PEND_VM()                                                                  \
    /* F3 */                                                                   \
    STAGE_B(BUF, KS)                                                           \
    LDAF(aP, 0, OBUF, 0) LDAF(aP, 1, OBUF, 0) LDBF(BN, 0, OBUF, 0)             \
    MMAC(aQ, b23, 4, 2)                                                        \
    PEND()                                                                     \
    /* F4 */                                                                   \
    STAGE_A(BUF, KS)                                                           \
    LDAF(aP, 2, OBUF, 0) LDAF(aP, 3, OBUF, 0) LDBF(BN, 1, OBUF, 0)             \
    MMAC(aQ, BC, 4, 0)                                                         \
    PEND() }

    // Prologue: stage tiles 0 (buf0) and 1 (buf1); wait tile 0 (8 oldest of
    // 16); read a0(0)+b01(0) so tile0-F1 has its operands one phase ahead.
    STAGE_A(0, 0)
    STAGE_B(0, 0)
    STAGE_B(1, BK)
    STAGE_A(1, BK)
    asm volatile("s_waitcnt vmcnt(8)" ::: "memory");
    __builtin_amdgcn_s_barrier();
    asm volatile("" ::: "memory");
    LDAF(aP, 0, 0, 0) LDAF(aP, 1, 0, 0) LDAF(aP, 2, 0, 0) LDAF(aP, 3, 0, 0)
    LDBF(b01E, 0, 0, 0) LDBF(b01E, 1, 0, 0)

#pragma unroll 1
    for (int t = 0; t < NT; t += 2) {
        const int k2 = ((t + 2) & (NT - 1)) * BK;  // wraps harmlessly at tail
        const int k3 = ((t + 3) & (NT - 1)) * BK;
        TILE(0, 1, b01E, b01O, k2)
        TILE(1, 0, b01O, b01E, k3)
    }
    asm volatile("s_waitcnt vmcnt(0) lgkmcnt(0)" ::: "memory");

    // Epilogue: C/D layout col = l&15, row = (l>>4)*4 + i.
    float bv[4];
#pragma unroll
    for (int nf = 0; nf < 4; ++nf) bv[nf] = bias[n0 + wn * 64 + nf * 16 + fr];
    const int r0 = m0 + wm * 128 + g * 4;
#pragma unroll
    for (int mh = 0; mh < 2; ++mh)
#pragma unroll
        for (int mf = 0; mf < 4; ++mf)
#pragma unroll
            for (int nf = 0; nf < 4; ++nf) {
                const int col = n0 + wn * 64 + nf * 16 + fr;
#pragma unroll
                for (int i = 0; i < 4; ++i)
                    C[(size_t)(r0 + mh * 64 + mf * 16 + i) * OUT_F + col] =
                        acc[mh * 4 + mf][nf][i] + bv[nf];
            }
}

extern "C" void kernel_launch(void* const* d_in, const int* in_sizes, int n_in,
                              void* d_out, int out_size, void* d_ws, size_t ws_size,
                              hipStream_t stream) {
    const float* x    = (const float*)d_in[0];
    const float* w    = (const float*)d_in[1];
    const float* bias = (const float*)d_in[2];
    const int*   row  = (const int*)d_in[3];
    const int*   col  = (const int*)d_in[4];
    float* out = (float*)d_out;
    const int nnz = in_sizes[3];

    // Workspace: xb (67 MB) + Wb (33.5 MB) in d_ws. Winner-index array M
    // (67 MB) borrows d_out (134 MB) -- GEMM overwrites it later.
    __bf16* xb = (__bf16*)d_ws;
    __bf16* Wb = (__bf16*)((char*)d_ws + (size_t)TOKENS * IN_F * 2);
    int* M = (int*)d_out;

    static bool attr_done = false;
    if (!attr_done) {
        hipFuncSetAttribute(reinterpret_cast<const void*>(gemm256_kernel),
                            hipFuncAttributeMaxDynamicSharedMemorySize, 131072);
        attr_done = true;
    }

    hipMemsetAsync(M, 0xFF, (size_t)OUT_F * IN_F * 4, stream);  // M = -1

    scatter_max_kernel<<<(nnz + 255) / 256, 256, 0, stream>>>(row, col, M, nnz);

    const int eb = OUT_F * IN_F / (256 * 8);        // 8192 extract blocks
    const int cb = TOKENS * IN_F / (256 * 8);       // 16384 convert blocks
    extract_convert_kernel<<<eb + cb, 256, 0, stream>>>(M, w, Wb, x, xb, eb);

    dim3 grid(OUT_F / 256, TOKENS / 256);           // (16, 32) = 512 wgs
    gemm256_kernel<<<grid, 512, 131072, stream>>>(xb, Wb, bias, out);
}